// Round 1
// baseline (1428.006 us; speedup 1.0000x reference)
//
#include <hip/hip_runtime.h>
#include <math.h>

// Problem shape (fixed by reference): B=256, F_IN=1024, F_OUT=1024
#define BATCH 256
#define FIN   1024
#define FOUT  1024

typedef float f4 __attribute__((ext_vector_type(4)));

__device__ __forceinline__ float softplus_f(float x) {
    // numerically stable: max(x,0) + log1p(exp(-|x|))
    return fmaxf(x, 0.0f) + log1pf(expf(-fabsf(x)));
}

// K1: sw[o,i] = softplus(weight_rho[o,i])  (1M elements, 4 per thread)
__global__ void __launch_bounds__(256) sp_precompute(const float* __restrict__ rho,
                                                     float* __restrict__ sw) {
    int i = (blockIdx.x * 256 + threadIdx.x) * 4;
    f4 r = *(const f4*)(rho + i);
    f4 s;
    s.x = softplus_f(r.x);
    s.y = softplus_f(r.y);
    s.z = softplus_f(r.z);
    s.w = softplus_f(r.w);
    *(f4*)(sw + i) = s;
}

// K2: one wave per (b,o). acc = sum_i x[b,i] * (mu[o,i] + sw[o,i]*eps_w[b,o,i])
// PRE=true: swrho holds precomputed softplus; PRE=false: swrho holds raw rho.
template <bool PRE>
__global__ void __launch_bounds__(256) bayes_linear_main(
    const float* __restrict__ x,       // (B, FIN)
    const float* __restrict__ mu,      // (FOUT, FIN)
    const float* __restrict__ swrho,   // (FOUT, FIN)
    const float* __restrict__ bmu,     // (FOUT)
    const float* __restrict__ brho,    // (FOUT)
    const float* __restrict__ eps_w,   // (B, FOUT, FIN)
    const float* __restrict__ eps_b,   // (B, FOUT)
    float* __restrict__ out)           // (B, FOUT)
{
    const int wave = (blockIdx.x << 2) + (threadIdx.x >> 6); // global (b,o) pair index
    const int lane = threadIdx.x & 63;
    const int b = wave >> 10;        // / FOUT
    const int o = wave & (FOUT - 1); // % FOUT

    const float* xr  = x     + (size_t)b * FIN;
    const float* mur = mu    + (size_t)o * FIN;
    const float* swr = swrho + (size_t)o * FIN;
    const float* er  = eps_w + (size_t)wave * FIN;

    float acc = 0.0f;
#pragma unroll
    for (int c = 0; c < 4; ++c) {
        const int idx = c * 256 + lane * 4;
        f4 xe = *(const f4*)(xr  + idx);   // L1-resident (shared across block's waves)
        f4 me = *(const f4*)(mur + idx);   // L2/L3-resident (reused across b)
        f4 se = *(const f4*)(swr + idx);   // L2/L3-resident
        f4 ee = __builtin_nontemporal_load((const f4*)(er + idx)); // HBM stream, no reuse

        if (!PRE) {
            se.x = softplus_f(se.x);
            se.y = softplus_f(se.y);
            se.z = softplus_f(se.z);
            se.w = softplus_f(se.w);
        }

        acc = fmaf(xe.x, fmaf(se.x, ee.x, me.x), acc);
        acc = fmaf(xe.y, fmaf(se.y, ee.y, me.y), acc);
        acc = fmaf(xe.z, fmaf(se.z, ee.z, me.z), acc);
        acc = fmaf(xe.w, fmaf(se.w, ee.w, me.w), acc);
    }

    // wave-wide butterfly reduction (64 lanes)
#pragma unroll
    for (int off = 32; off > 0; off >>= 1)
        acc += __shfl_xor(acc, off, 64);

    if (lane == 0) {
        float bias = bmu[o] + softplus_f(brho[o]) * eps_b[wave];
        out[wave] = acc + bias;
    }
}

extern "C" void kernel_launch(void* const* d_in, const int* in_sizes, int n_in,
                              void* d_out, int out_size, void* d_ws, size_t ws_size,
                              hipStream_t stream) {
    const float* x     = (const float*)d_in[0];
    const float* wmu   = (const float*)d_in[1];
    const float* wrho  = (const float*)d_in[2];
    const float* bmu   = (const float*)d_in[3];
    const float* brho  = (const float*)d_in[4];
    const float* eps_w = (const float*)d_in[5];
    const float* eps_b = (const float*)d_in[6];
    float* out = (float*)d_out;

    const size_t sw_bytes = (size_t)FOUT * FIN * sizeof(float); // 4 MiB
    const int n_pairs = BATCH * FOUT;           // 262144 waves
    const int main_blocks = n_pairs / 4;        // 4 waves / 256-thread block

    if (ws_size >= sw_bytes) {
        float* sw = (float*)d_ws;
        sp_precompute<<<(FOUT * FIN) / (256 * 4), 256, 0, stream>>>(wrho, sw);
        bayes_linear_main<true><<<main_blocks, 256, 0, stream>>>(
            x, wmu, sw, bmu, brho, eps_w, eps_b, out);
    } else {
        bayes_linear_main<false><<<main_blocks, 256, 0, stream>>>(
            x, wmu, wrho, bmu, brho, eps_w, eps_b, out);
    }
}